// Round 1
// 313.366 us; speedup vs baseline: 1.0004x; 1.0004x over previous
//
#include <hip/hip_runtime.h>
#include <hip/hip_fp16.h>

#define M_DIM 16384
#define K_DIM 2048
#define N_DIM 2048

#define BM 256
#define BN 256
#define BK 128
#define NT (K_DIM / BK)

typedef int int4v  __attribute__((ext_vector_type(4)));
typedef int int16v __attribute__((ext_vector_type(16)));

__device__ __forceinline__ void gl_lds16(const void* g, void* l) {
    __builtin_amdgcn_global_load_lds(
        (const __attribute__((address_space(1))) void*)g,
        (__attribute__((address_space(3))) void*)l,
        16, 0, 0);
}

__device__ __forceinline__ int pack4(int4v v) {
    return (v[0] & 255) | ((v[1] & 255) << 8) | ((v[2] & 255) << 16) | (v[3] << 24);
}

// x: int32 [M,K] -> int8 [M,K]; lane-contiguous loads/stores
__global__ void pack_x_kernel(const int* __restrict__ x, char* __restrict__ xp) {
    const int4v* src = (const int4v*)x;
    int* dst = (int*)xp;
    int base = blockIdx.x * 1024 + threadIdx.x;
#pragma unroll
    for (int j = 0; j < 4; ++j) {
        int i = base + j * 256;
        dst[i] = pack4(src[i]);
    }
}

// weight: int32 [K,N] -> int8 WT [N,K] (transpose + pack), 64x64 tiles via LDS
__global__ void wt_pack_kernel(const int* __restrict__ w, char* __restrict__ wt) {
    __shared__ char tile[64][68];
    int b  = blockIdx.x;
    int k0 = (b & 31) * 64;
    int n0 = (b >> 5) * 64;
    int t  = threadIdx.x;
    int r  = t >> 2;
    int c  = (t & 3) * 16;

    const int* src = w + (size_t)(k0 + r) * N_DIM + n0 + c;
    int4v a = *(const int4v*)(src + 0);
    int4v bb = *(const int4v*)(src + 4);
    int4v cc = *(const int4v*)(src + 8);
    int4v dd = *(const int4v*)(src + 12);
    *(int*)&tile[r][c + 0]  = pack4(a);
    *(int*)&tile[r][c + 4]  = pack4(bb);
    *(int*)&tile[r][c + 8]  = pack4(cc);
    *(int*)&tile[r][c + 12] = pack4(dd);
    __syncthreads();

    char buf[16];
#pragma unroll
    for (int j = 0; j < 16; ++j) buf[j] = tile[c + j][r];
    *(int4v*)(wt + (size_t)(n0 + r) * K_DIM + k0 + c) = *(int4v*)buf;
}

// GEMM: A int8 [M,K], BT int8 [N,K] -> C fp32 [M,N] (+bias)
// 256x256 tile, BK=128, 512 thr = 8 waves (2M x 4N), wave tile 128x64 =
// acc[4][2] of 32x32x32 i8 MFMA. Double-buffered LDS (2 x 64 KiB = 128 KiB,
// 1 block/CU). 4 phases per K-tile (one per MFMA k-step), m201-style:
//   {6 ds_read_b128 | staged gl_lds prefetch} -> barrier -> lgkmcnt(0) ->
//   setprio(1) -> 8 MFMA -> setprio(0) -> [vmcnt(0) @ ks==3] -> barrier
// Prefetch of tile t+1 issues at phases 0-1 of tile t (A then B), drains once
// at end of phase 3 -> ~1.5k cycles of compute hide the load latency.
// LDS layout (16B slots, XOR-swizzled): slot = r*8 + (cg ^ (r&7)) holds
// row r, k-chunk cg*16..+16. Staging is slot-linear (gl_lds wave-uniform dest)
// with pre-swizzled global source; fragment reads cover all 32 banks per
// 8-lane group (slot%8 = (2ks+khl)^l7 distinct) -> conflict-free.
__global__ __launch_bounds__(512, 2)
void gemm_i8_kernel(const char* __restrict__ A, const char* __restrict__ BT,
                    const __half* __restrict__ bias, float* __restrict__ C) {
    __shared__ char Asm[2][BM * BK];   // 2 x 32768 B
    __shared__ char Bsm[2][BN * BK];   // 2 x 32768 B

    const int bid = blockIdx.x;
    const int mt = bid & 63;            // 64 M-tiles, m fastest (B-panel stays hot)
    const int nt = bid >> 6;            // 8 N-tiles
    const int R0 = mt * BM, C0 = nt * BN;

    const int t = threadIdx.x;
    const int lane = t & 63;
    const int w = t >> 6;
    const int wm = w >> 2;              // 0..1 row-half
    const int wn = w & 3;               // 0..3 col-quarter
    const int l31 = lane & 31, l7 = lane & 7, khl = lane >> 5;

    int16v acc[4][2];
#pragma unroll
    for (int i = 0; i < 4; ++i)
#pragma unroll
        for (int j = 0; j < 2; ++j) acc[i][j] = (int16v)0;

    // staging: thread owns slots t + 512*j; slot s -> row s>>3, stored chunk s&7,
    // global chunk cg = (s&7)^(row&7)
    unsigned aoffu[4], boffu[4];
    int ldst[4];
#pragma unroll
    for (int j = 0; j < 4; ++j) {
        int s = t + j * 512;
        int r = s >> 3;
        int cg = (s & 7) ^ (r & 7);
        aoffu[j] = (unsigned)(R0 + r) * K_DIM + cg * 16;
        boffu[j] = (unsigned)(C0 + r) * K_DIM + cg * 16;
        ldst[j] = s * 16;
    }

    // fragment row-slot bases (row*8); row&7 == l7 since bases are mult. of 32
    int arows[4], brows[2];
#pragma unroll
    for (int i = 0; i < 4; ++i) arows[i] = (wm * 128 + i * 32 + l31) * 8;
#pragma unroll
    for (int j = 0; j < 2; ++j) brows[j] = (wn * 64 + j * 32 + l31) * 8;

    // prologue: stage tile 0 -> buffer 0, full drain
#pragma unroll
    for (int j = 0; j < 4; ++j) gl_lds16(A + aoffu[j], &Asm[0][ldst[j]]);
#pragma unroll
    for (int j = 0; j < 4; ++j) gl_lds16(BT + boffu[j], &Bsm[0][ldst[j]]);
    asm volatile("s_waitcnt vmcnt(0)" ::: "memory");
    __builtin_amdgcn_s_barrier();

#define TILE(cur, kt)                                                           \
    {                                                                           \
        const int knext = ((kt) + 1) * BK;                                      \
        const bool pf = ((kt) + 1 < NT);                                        \
        _Pragma("unroll")                                                       \
        for (int ks = 0; ks < 4; ++ks) {                                        \
            int4v af[4], bf[2];                                                 \
            const int ch = (2 * ks + khl) ^ l7;                                 \
            _Pragma("unroll")                                                   \
            for (int i = 0; i < 4; ++i)                                         \
                af[i] = *(const int4v*)&Asm[cur][(arows[i] + ch) * 16];         \
            _Pragma("unroll")                                                   \
            for (int j = 0; j < 2; ++j)                                         \
                bf[j] = *(const int4v*)&Bsm[cur][(brows[j] + ch) * 16];         \
            if (ks == 0 && pf) {                                                \
                _Pragma("unroll")                                               \
                for (int j = 0; j < 4; ++j)                                     \
                    gl_lds16(A + aoffu[j] + knext, &Asm[(cur) ^ 1][ldst[j]]);   \
            }                                                                   \
            if (ks == 1 && pf) {                                                \
                _Pragma("unroll")                                               \
                for (int j = 0; j < 4; ++j)                                     \
                    gl_lds16(BT + boffu[j] + knext, &Bsm[(cur) ^ 1][ldst[j]]);  \
            }                                                                   \
            __builtin_amdgcn_s_barrier();                                       \
            asm volatile("s_waitcnt lgkmcnt(0)" ::: "memory");                  \
            __builtin_amdgcn_s_setprio(1);                                      \
            _Pragma("unroll")                                                   \
            for (int i = 0; i < 4; ++i) {                                       \
                _Pragma("unroll")                                               \
                for (int j = 0; j < 2; ++j)                                     \
                    acc[i][j] = __builtin_amdgcn_mfma_i32_32x32x32_i8(          \
                        af[i], bf[j], acc[i][j], 0, 0, 0);                      \
            }                                                                   \
            __builtin_amdgcn_s_setprio(0);                                      \
            if (ks == 3) asm volatile("s_waitcnt vmcnt(0)" ::: "memory");       \
            __builtin_amdgcn_s_barrier();                                       \
        }                                                                       \
    }

    for (int kt = 0; kt < NT; kt += 2) {
        TILE(0, kt)
        TILE(1, kt + 1)
    }
#undef TILE

    // epilogue: C/D layout col=lane&31, row=(reg&3)+8*(reg>>2)+4*(lane>>5)
    const int col = l31;
    const int rb = khl * 4;
#pragma unroll
    for (int j = 0; j < 2; ++j) {
        const int cn = C0 + wn * 64 + j * 32 + col;
        const float bv = __half2float(bias[cn]);
#pragma unroll
        for (int i = 0; i < 4; ++i) {
            const int rm = R0 + wm * 128 + i * 32 + rb;
#pragma unroll
            for (int reg = 0; reg < 16; ++reg) {
                const int row = rm + (reg & 3) + 8 * (reg >> 2);
                C[(size_t)row * N_DIM + cn] = (float)acc[i][j][reg] + bv;
            }
        }
    }
}

extern "C" void kernel_launch(void* const* d_in, const int* in_sizes, int n_in,
                              void* d_out, int out_size, void* d_ws, size_t ws_size,
                              hipStream_t stream) {
    const int* x = (const int*)d_in[0];
    const int* wgt = (const int*)d_in[1];
    const __half* bias = (const __half*)d_in[2];
    float* out = (float*)d_out;

    char* xp = (char*)d_ws;                                   // 32 MiB packed A
    char* wt = (char*)d_ws + (size_t)M_DIM * K_DIM;           // 4 MiB packed W^T

    pack_x_kernel<<<(M_DIM * (size_t)K_DIM) / 4 / 1024, 256, 0, stream>>>(x, xp);
    wt_pack_kernel<<<(K_DIM / 64) * (N_DIM / 64), 256, 0, stream>>>(wgt, wt);
    gemm_i8_kernel<<<(M_DIM / BM) * (N_DIM / BN), 512, 0, stream>>>(xp, wt, bias, out);
}